// Round 5
// baseline (64.818 us; speedup 1.0000x reference)
//
#include <hip/hip_runtime.h>
#include <hip/hip_bf16.h>

#define B_SZ 256
#define L_SZ 50
#define N_SZ 100000
#define D_SZ 128
#define NBT ((N_SZ + 63) / 64)   // 1563 col-tiles of 64 (tail tile = 32 cols)

typedef __attribute__((ext_vector_type(8))) short bf16x8;
typedef __attribute__((ext_vector_type(4))) float f32x4;

__device__ inline unsigned short f2bf(float f) {
    union { float f; unsigned u; } v; v.f = f;
    unsigned r = v.u + 0x7FFFu + ((v.u >> 16) & 1u);   // round-to-nearest-even
    return (unsigned short)(r >> 16);
}

// ---------------- kernel 1 (fused prep+ub): per-b, gather v, qW1/qW2 local, u -> bf16
__global__ __launch_bounds__(128) void k_ub(const int* __restrict__ seeds,
                                            const float* __restrict__ E,
                                            const float* __restrict__ pe,
                                            const float* __restrict__ W1,
                                            const float* __restrict__ W2,
                                            const float* __restrict__ q,
                                            const float* __restrict__ b_att,
                                            unsigned short* __restrict__ u_bf,
                                            float* __restrict__ loss_slot) {
    __shared__ float vbuf[L_SZ][D_SZ + 1];   // +1 pad: conflict-free row sweeps
    __shared__ float att[L_SZ];
    __shared__ float qs[D_SZ], qw1s[D_SZ], qw2s[D_SZ];
    __shared__ float c2s, qsums;
    int b = blockIdx.x, d = threadIdx.x;
    qs[d] = q[d];

    for (int l = 0; l < L_SZ; ++l) {
        int s = seeds[b * L_SZ + l];
        vbuf[l][d] = E[(size_t)s * D_SZ + d] + pe[l * D_SZ + d];
    }
    __syncthreads();

    // qW1[d] = sum_e q[e] W1[e,d]  (redundant per block; W1/W2 are L2-resident)
    float a1 = 0.f, a2 = 0.f;
    #pragma unroll 4
    for (int e = 0; e < D_SZ; ++e) {
        float qe = qs[e];
        a1 += qe * W1[e * D_SZ + d];
        a2 += qe * W2[e * D_SZ + d];
    }
    qw1s[d] = a1;
    qw2s[d] = a2;
    __syncthreads();

    if (d < L_SZ) {                 // att_raw[l] = v[l,:] . qW1
        float acc = 0.f;
        #pragma unroll 4
        for (int k = 0; k < D_SZ; ++k) acc += vbuf[d][k] * qw1s[k];
        att[d] = acc;
    } else if (d == L_SZ) {         // c2 = vn . qW2
        float acc = 0.f;
        #pragma unroll 4
        for (int k = 0; k < D_SZ; ++k) acc += vbuf[L_SZ - 1][k] * qw2s[k];
        c2s = acc;
    } else if (d == L_SZ + 1) {     // qsum
        float s = 0.f;
        for (int i = 0; i < D_SZ; ++i) s += qs[i];
        qsums = s;
    }
    __syncthreads();

    float add = c2s + b_att[0] * qsums;
    float u = 0.f;
    #pragma unroll 5
    for (int l = 0; l < L_SZ; ++l) u += (att[l] + add) * vbuf[l][d];
    u_bf[b * D_SZ + d] = f2bf(u);

    if (b == 0 && d == 0) loss_slot[0] = 0.f;   // zero loss accumulator (k_loss runs later)
}

// ---------------- kernel 2: scores = u @ E^T + bias (bf16 MFMA)
// 256 threads = 4 waves; block = 64 n-cols x 128 b-rows (u half, 32 KB LDS,
// XOR-swizzled byte ^= (row&7)<<4). grid = NBT*2 (bit0 = row half) -> 4 blocks/CU,
// phases interleave across blocks. rs-outer: each rs's store+exp is inside the
// MFMA loop so the 102 MB write stream is spread, not a terminal burst.
// D layout: row=(lane>>4)*4+g -> n, col=lane&15 -> b  => 16B stores per lane.
__global__ __launch_bounds__(256, 4) void k_gemm(const float* __restrict__ E,
                                                 const float* __restrict__ out_bias,
                                                 const unsigned short* __restrict__ u_bf,
                                                 float* __restrict__ scores,
                                                 float* __restrict__ partial) {
    __shared__ unsigned short us[128 * D_SZ];    // 32 KB swizzled u-half
    __shared__ float lds_sum[128];
    int tid = threadIdx.x;
    int w = tid >> 6, lane = tid & 63;
    int tile = blockIdx.x >> 1, hf = blockIdx.x & 1;
    if (tid < 128) lds_sum[tid] = 0.f;

    // ---- stage 32 KB: 8 passes x 256 thr x 16B, coalesced reads, swizzled writes
    const char* ub = (const char*)u_bf + hf * 32768;
    #pragma unroll
    for (int r = 0; r < 8; ++r) {
        int off = r * 4096 + tid * 16;
        int b = off >> 8, inrow = off & 255;
        bf16x8 v = *(const bf16x8*)(ub + off);
        *(bf16x8*)((char*)us + b * 256 + (inrow ^ ((b & 7) << 4))) = v;
    }

    int nc = tile * 64 + w * 16;                 // this wave's 16-col panel
    bool valid = (nc < N_SZ);                    // wave-uniform (N_SZ % 16 == 0)
    int lo = lane & 15, hi = lane >> 4;
    int kb = hi * 8;

    // ---- A fragments: E rows (= score cols), f32 -> bf16 in regs
    long erow = valid ? (nc + lo) : 0;
    bf16x8 efrag[4];
    #pragma unroll
    for (int ks = 0; ks < 4; ++ks) {
        const float* p = E + (size_t)erow * D_SZ + ks * 32 + kb;
        float4 x = *(const float4*)p;
        float4 y = *(const float4*)(p + 4);
        bf16x8 f;
        f[0] = (short)f2bf(x.x); f[1] = (short)f2bf(x.y);
        f[2] = (short)f2bf(x.z); f[3] = (short)f2bf(x.w);
        f[4] = (short)f2bf(y.x); f[5] = (short)f2bf(y.y);
        f[6] = (short)f2bf(y.z); f[7] = (short)f2bf(y.w);
        efrag[ks] = f;
    }
    int nb = valid ? (nc + hi * 4) : 0;          // this lane's 4 consecutive n
    float4 bias4 = *(const float4*)(out_bias + nb);

    __syncthreads();                             // u staged; lds_sum zeroed

    #pragma unroll
    for (int rs = 0; rs < 8; ++rs) {
        f32x4 acc = (f32x4){0.f, 0.f, 0.f, 0.f};
        #pragma unroll
        for (int ks = 0; ks < 4; ++ks) {
            int b = rs * 16 + lo;
            int kcol = ks * 64 + hi * 16;
            bf16x8 uf = *(const bf16x8*)((const char*)us + b * 256 + (kcol ^ ((b & 7) << 4)));
            acc = __builtin_amdgcn_mfma_f32_16x16x32_bf16(efrag[ks], uf, acc, 0, 0, 0);
        }
        int jl = rs * 16 + lo;                   // local b-row
        int jr = hf * 128 + jl;                  // global b-row
        f32x4 c;
        c[0] = acc[0] + bias4.x;
        c[1] = acc[1] + bias4.y;
        c[2] = acc[2] + bias4.z;
        c[3] = acc[3] + bias4.w;
        if (valid)
            *(f32x4*)(scores + (size_t)jr * N_SZ + nb) = c;
        float p = __expf(c[0]) + __expf(c[1]) + __expf(c[2]) + __expf(c[3]);
        p += __shfl_xor(p, 16);
        p += __shfl_xor(p, 32);                  // lanes {l, l^16, l^32, l^48} share jl
        if (valid && hi == 0) atomicAdd(&lds_sum[jl], p);
    }
    __syncthreads();
    if (tid < 128) partial[(size_t)tile * B_SZ + hf * 128 + tid] = lds_sum[tid];
}

// ---------------- kernel 3: per-row logsumexp + NLL mean
__global__ __launch_bounds__(256) void k_loss(const float* __restrict__ partial,
                                              const float* __restrict__ scores,
                                              const int* __restrict__ labels,
                                              float* __restrict__ out_loss) {
    int b = blockIdx.x, t = threadIdx.x;
    float acc = 0.f;
    for (int i = t; i < NBT; i += 256) acc += partial[(size_t)i * B_SZ + b];
    __shared__ float red[256];
    red[t] = acc;
    __syncthreads();
    for (int s = 128; s > 0; s >>= 1) {
        if (t < s) red[t] += red[t + s];
        __syncthreads();
    }
    if (t == 0) {
        int lab = labels[b];
        float val = scores[(size_t)b * N_SZ + lab] - logf(red[0]);
        atomicAdd(out_loss, -val * (1.0f / (float)B_SZ));
    }
}

extern "C" void kernel_launch(void* const* d_in, const int* in_sizes, int n_in,
                              void* d_out, int out_size, void* d_ws, size_t ws_size,
                              hipStream_t stream) {
    const int*   seeds    = (const int*)d_in[0];
    const int*   labels   = (const int*)d_in[1];
    const float* E        = (const float*)d_in[2];
    const float* W1       = (const float*)d_in[3];
    const float* W2       = (const float*)d_in[4];
    const float* q        = (const float*)d_in[5];
    const float* b_att    = (const float*)d_in[6];
    const float* out_bias = (const float*)d_in[7];
    const float* pe       = (const float*)d_in[8];

    float* scores = (float*)d_out;
    float* loss   = scores + (size_t)B_SZ * N_SZ;

    // ws layout: @2048 u_bf16 (64KB) | @67584 partial (1563*256*4 = 1.6MB)
    unsigned short* u_bf    = (unsigned short*)((char*)d_ws + 2048);
    float*          partial = (float*)((char*)d_ws + 67584);

    k_ub<<<B_SZ, 128, 0, stream>>>(seeds, E, pe, W1, W2, q, b_att, u_bf, loss);
    k_gemm<<<NBT * 2, 256, 0, stream>>>(E, out_bias, u_bf, scores, partial);
    k_loss<<<B_SZ, 256, 0, stream>>>(partial, scores, labels, loss);
}